// Round 1
// baseline (49.367 us; speedup 1.0000x reference)
//
#include <hip/hip_runtime.h>

// Unfolder: out[b,c,p,q] = x[b,c, p/3 + p%3 - 1, q/3 + q%3 - 1], zero outside.
// B=8, C=3, H=W=512, k=3, pad=1 -> out is [8,3,1536,1536] fp32.

#define B_N 8
#define C_N 3
#define H_N 512
#define W_N 512
#define HO 1536   // 3*(H+2*1-3+1) = 3*512
#define WO 1536

__global__ __launch_bounds__(384) void unfold_rows_kernel(
    const float* __restrict__ x, float* __restrict__ out)
{
    const int p  = blockIdx.x;   // output row within image [0,1536)
    const int bc = blockIdx.y;   // fused batch*channel  [0,24)

    // source input row (block-uniform); -1 or 512 => entire row is zero
    const int s = p / 3 + p % 3 - 1;

    float4* orow = reinterpret_cast<float4*>(out + ((size_t)bc * HO + p) * WO);
    const int j = threadIdx.x;   // one float4 (4 output cols) per thread

    float4 v = make_float4(0.f, 0.f, 0.f, 0.f);
    if ((unsigned)s < (unsigned)H_N) {
        const float* __restrict__ xrow = x + ((size_t)bc * H_N + s) * W_N;
        const int q0 = j * 4;
        float vals[4];
#pragma unroll
        for (int e = 0; e < 4; ++e) {
            const int q = q0 + e;
            const int t = q / 3 + q % 3 - 1;     // source col, in [-1, 512]
            vals[e] = ((unsigned)t < (unsigned)W_N) ? xrow[t] : 0.f;
        }
        v = make_float4(vals[0], vals[1], vals[2], vals[3]);
    }
    orow[j] = v;
}

extern "C" void kernel_launch(void* const* d_in, const int* in_sizes, int n_in,
                              void* d_out, int out_size, void* d_ws, size_t ws_size,
                              hipStream_t stream)
{
    const float* x = (const float*)d_in[0];
    float* out = (float*)d_out;

    dim3 grid(HO, B_N * C_N);   // one block per output row
    dim3 block(WO / 4);         // 384 threads, one float4 each
    unfold_rows_kernel<<<grid, block, 0, stream>>>(x, out);
}

// Round 2
// 48.715 us; speedup vs baseline: 1.0134x; 1.0134x over previous
//
#include <hip/hip_runtime.h>

// Unfolder: out[b,c,p,q] = x[b,c, p/3 + p%3 - 1, q/3 + q%3 - 1], zero outside.
// B=8, C=3, H=W=512, k=3, pad=1 -> out is [8,3,1536,1536] fp32.
//
// Block a handles output rows p = 3a..3a+2, which read input rows
// s = a-1, a, a+1 (p=3a+d -> s = a+d-1). Stage those 3 rows in LDS via
// coalesced float4 loads, then gather + 3 coalesced float4 stores.

#define B_N 8
#define C_N 3
#define H_N 512
#define W_N 512
#define HO 1536
#define WO 1536

__global__ __launch_bounds__(384) void unfold_lds_kernel(
    const float* __restrict__ x, float* __restrict__ out)
{
    const int a  = blockIdx.x;   // row group [0,512)
    const int bc = blockIdx.y;   // fused batch*channel [0,24)
    const int tid = threadIdx.x; // [0,384)

    __shared__ float rows[3][W_N];   // r=0 -> s=a-1, r=1 -> s=a, r=2 -> s=a+1

    // Stage: 3*512 floats = 384 float4, one per thread, coalesced.
    {
        const int r  = tid >> 7;        // /128  (128 float4 per row)
        const int cc = tid & 127;       // float4 index within row
        const int s  = a - 1 + r;
        float4 v = make_float4(0.f, 0.f, 0.f, 0.f);
        if ((unsigned)s < (unsigned)H_N) {
            v = reinterpret_cast<const float4*>(
                    x + ((size_t)bc * H_N + s) * W_N)[cc];
        }
        reinterpret_cast<float4*>(&rows[r][0])[cc] = v;
    }
    __syncthreads();

    // Gather columns: q = 4*tid + e, t = q/3 + q%3 - 1 (in [-1, 512]).
    int tcol[4];
#pragma unroll
    for (int e = 0; e < 4; ++e) {
        const int q = tid * 4 + e;
        tcol[e] = q / 3 + q % 3 - 1;
    }

    const size_t obase = ((size_t)bc * HO + 3 * (size_t)a) * WO;
#pragma unroll
    for (int d = 0; d < 3; ++d) {      // output row p = 3a+d uses LDS row r=d
        float vals[4];
#pragma unroll
        for (int e = 0; e < 4; ++e) {
            const int t = tcol[e];
            vals[e] = ((unsigned)t < (unsigned)W_N) ? rows[d][t] : 0.f;
        }
        reinterpret_cast<float4*>(out + obase + (size_t)d * WO)[tid] =
            make_float4(vals[0], vals[1], vals[2], vals[3]);
    }
}

extern "C" void kernel_launch(void* const* d_in, const int* in_sizes, int n_in,
                              void* d_out, int out_size, void* d_ws, size_t ws_size,
                              hipStream_t stream)
{
    const float* x = (const float*)d_in[0];
    float* out = (float*)d_out;

    dim3 grid(H_N, B_N * C_N);   // one block per 3-row output group
    dim3 block(WO / 4);          // 384 threads
    unfold_lds_kernel<<<grid, block, 0, stream>>>(x, out);
}

// Round 4
// 47.768 us; speedup vs baseline: 1.0335x; 1.0198x over previous
//
#include <hip/hip_runtime.h>

// Unfolder: out[b,c,p,q] = x[b,c, p/3 + p%3 - 1, q/3 + q%3 - 1], zero outside.
// B=8, C=3, H=W=512, k=3, pad=1 -> out is [8,3,1536,1536] fp32.
//
// Block a handles output rows p = 3a..3a+2 (input rows s = a-1, a, a+1).
// Stage rows in LDS (coalesced float4 loads), gather, then 3 coalesced
// NONTEMPORAL 16B stores (streaming 226 MB out; keep L2 for the input).

#define B_N 8
#define C_N 3
#define H_N 512
#define W_N 512
#define HO 1536
#define WO 1536

typedef float fvec4 __attribute__((ext_vector_type(4)));

__global__ __launch_bounds__(384) void unfold_lds_nt_kernel(
    const float* __restrict__ x, float* __restrict__ out)
{
    const int a  = blockIdx.x;   // row group [0,512)
    const int bc = blockIdx.y;   // fused batch*channel [0,24)
    const int tid = threadIdx.x; // [0,384)

    __shared__ float rows[3][W_N];

    // Stage: 3*512 floats = 384 float4, one per thread, coalesced.
    {
        const int r  = tid >> 7;        // row 0..2
        const int cc = tid & 127;       // float4 index within row
        const int s  = a - 1 + r;
        fvec4 v = (fvec4)0.f;
        if ((unsigned)s < (unsigned)H_N) {
            v = reinterpret_cast<const fvec4*>(
                    x + ((size_t)bc * H_N + s) * W_N)[cc];
        }
        reinterpret_cast<fvec4*>(&rows[r][0])[cc] = v;
    }
    __syncthreads();

    // Gather columns: q = 4*tid + e, t = q/3 + q%3 - 1 (in [-1, 512]).
    int tcol[4];
#pragma unroll
    for (int e = 0; e < 4; ++e) {
        const int q = tid * 4 + e;
        tcol[e] = q / 3 + q % 3 - 1;
    }

    const size_t obase = ((size_t)bc * HO + 3 * (size_t)a) * WO;
#pragma unroll
    for (int d = 0; d < 3; ++d) {      // output row p = 3a+d uses LDS row r=d
        fvec4 v4;
#pragma unroll
        for (int e = 0; e < 4; ++e) {
            const int t = tcol[e];
            v4[e] = ((unsigned)t < (unsigned)W_N) ? rows[d][t] : 0.f;
        }
        __builtin_nontemporal_store(
            v4, reinterpret_cast<fvec4*>(out + obase + (size_t)d * WO) + tid);
    }
}

extern "C" void kernel_launch(void* const* d_in, const int* in_sizes, int n_in,
                              void* d_out, int out_size, void* d_ws, size_t ws_size,
                              hipStream_t stream)
{
    const float* x = (const float*)d_in[0];
    float* out = (float*)d_out;

    dim3 grid(H_N, B_N * C_N);   // one block per 3-row output group
    dim3 block(WO / 4);          // 384 threads
    unfold_lds_nt_kernel<<<grid, block, 0, stream>>>(x, out);
}